// Round 2
// baseline (764.480 us; speedup 1.0000x reference)
//
#include <hip/hip_runtime.h>

#define BB 16
#define TT 750
#define FF 4096
#define CC 20
#define K_ACT 93
#define K_BKG 93
#define NROWS (BB * TT)   // 12000

// ---------------------------------------------------------------------------
// K1: fused  features-copy + masked GEMM (cas logits) + ||x||^2 (fp64)
// grid 3000 blocks, 4 rows/block, 256 threads, thread = 8 f's per 2048-chunk
// ---------------------------------------------------------------------------
__global__ __launch_bounds__(256) void k_main(
    const float* __restrict__ x, const float* __restrict__ w,
    const float* __restrict__ mask, float* __restrict__ features,
    float* __restrict__ cas_ws, double* __restrict__ mag2_ws)
{
    const int tid = threadIdx.x;
    const int row0 = blockIdx.x * 4;

    float acc[4][CC];
#pragma unroll
    for (int r = 0; r < 4; ++r)
#pragma unroll
        for (int c = 0; c < CC; ++c) acc[r][c] = 0.f;
    double mg[4] = {0.0, 0.0, 0.0, 0.0};

#pragma unroll
    for (int k = 0; k < 2; ++k) {
        const int fb = k * 2048 + tid * 8;
        float mk[4][8];
#pragma unroll
        for (int r = 0; r < 4; ++r) {
            const size_t off = (size_t)(row0 + r) * FF + fb;
            const float4 a0 = *(const float4*)(x + off);
            const float4 a1 = *(const float4*)(x + off + 4);
            const float4 m0 = *(const float4*)(mask + off);
            const float4 m1 = *(const float4*)(mask + off + 4);
            *(float4*)(features + off) = a0;      // pass-through output (bit-exact)
            *(float4*)(features + off + 4) = a1;
            mk[r][0] = a0.x * m0.x; mk[r][1] = a0.y * m0.y;
            mk[r][2] = a0.z * m0.z; mk[r][3] = a0.w * m0.w;
            mk[r][4] = a1.x * m1.x; mk[r][5] = a1.y * m1.y;
            mk[r][6] = a1.z * m1.z; mk[r][7] = a1.w * m1.w;
            mg[r] = fma((double)a0.x, (double)a0.x, mg[r]);
            mg[r] = fma((double)a0.y, (double)a0.y, mg[r]);
            mg[r] = fma((double)a0.z, (double)a0.z, mg[r]);
            mg[r] = fma((double)a0.w, (double)a0.w, mg[r]);
            mg[r] = fma((double)a1.x, (double)a1.x, mg[r]);
            mg[r] = fma((double)a1.y, (double)a1.y, mg[r]);
            mg[r] = fma((double)a1.z, (double)a1.z, mg[r]);
            mg[r] = fma((double)a1.w, (double)a1.w, mg[r]);
        }
#pragma unroll
        for (int c = 0; c < CC; ++c) {
            const float4 w0 = *(const float4*)(w + (size_t)c * FF + fb);
            const float4 w1 = *(const float4*)(w + (size_t)c * FF + fb + 4);
            float wf[8] = {w0.x, w0.y, w0.z, w0.w, w1.x, w1.y, w1.z, w1.w};
#pragma unroll
            for (int r = 0; r < 4; ++r)
#pragma unroll
                for (int j = 0; j < 8; ++j)
                    acc[r][c] = fmaf(mk[r][j], wf[j], acc[r][c]);
        }
    }

    __shared__ float red[CC][256];
    __shared__ float red2[CC][8];
    __shared__ double dred[256];
    __shared__ double dred2[8];

    for (int r = 0; r < 4; ++r) {
#pragma unroll
        for (int c = 0; c < CC; ++c) red[c][tid] = acc[r][c];
        dred[tid] = mg[r];
        __syncthreads();
        if (tid < 160) {
            const int c = tid >> 3, seg = tid & 7;
            const float4* p = (const float4*)&red[c][seg * 32];
            float s = 0.f;
#pragma unroll
            for (int i = 0; i < 8; ++i) { const float4 v = p[i]; s += (v.x + v.y) + (v.z + v.w); }
            red2[c][seg] = s;
        } else if (tid < 168) {
            const int seg = tid - 160;
            double s = 0.0;
#pragma unroll
            for (int i = 0; i < 32; ++i) s += dred[seg * 32 + i];
            dred2[seg] = s;
        }
        __syncthreads();
        if (tid < CC) {
            float s = 0.f;
#pragma unroll
            for (int i = 0; i < 8; ++i) s += red2[tid][i];
            cas_ws[(size_t)(row0 + r) * CC + tid] = s;
        } else if (tid == CC) {
            double s = 0.0;
#pragma unroll
            for (int i = 0; i < 8; ++i) s += dred2[i];
            mag2_ws[row0 + r] = s;
        }
        __syncthreads();
    }
}

// ---------------------------------------------------------------------------
// K2: exact jax.lax.top_k index selection (stable desc, lower index first)
// grid (16, 3), 256 threads; rank-count over alive entries, fp64 keys
// ---------------------------------------------------------------------------
__global__ __launch_bounds__(256) void k_topk(
    const double* __restrict__ mag2_ws, const float* __restrict__ smask,
    int* __restrict__ idxA, int* __restrict__ idxB)
{
    const int b = blockIdx.x;
    const int chunk = blockIdx.y;
    const int tid = threadIdx.x;

    __shared__ double m2[TT];
    __shared__ unsigned char alive[TT];
    __shared__ double mred[256];

    for (int t = tid; t < TT; t += 256) {
        m2[t] = mag2_ws[b * TT + t];
        alive[t] = (smask[b * TT + t] != 0.f);
    }
    __syncthreads();
    double lm = 0.0;
    for (int t = tid; t < TT; t += 256) lm = fmax(lm, m2[t]);
    mred[tid] = lm;
    __syncthreads();
    for (int s = 128; s > 0; s >>= 1) {
        if (tid < s) mred[tid] = fmax(mred[tid], mred[tid + s]);
        __syncthreads();
    }
    const double mx = mred[0];

    const int t = chunk * 250 + tid;
    if (tid < 250 && t < TT && alive[t]) {
        const double v = m2[t];
        const bool posB = v < mx;  // bkg key (mx - v)*s is positive
        int rA = 0, rB = 0;
        for (int u = 0; u < TT; ++u) {
            if (!alive[u]) continue;
            const double wv = m2[u];
            if (wv > v || (wv == v && u < t)) ++rA;
            if (posB && wv < mx && (wv < v || (wv == v && u < t))) ++rB;
        }
        if (rA < K_ACT) idxA[b * K_ACT + rA] = t;
        if (posB && rB < K_BKG) idxB[b * K_BKG + rB] = t;
    }
}

// ---------------------------------------------------------------------------
// K3: gather feat_act / feat_bkg rows (exact f32 row copies)
// ---------------------------------------------------------------------------
__global__ __launch_bounds__(256) void k_gather(
    const float* __restrict__ x, const int* __restrict__ idxA,
    const int* __restrict__ idxB, float* __restrict__ featA,
    float* __restrict__ featB)
{
    int g = blockIdx.x;                 // 0 .. 2*16*93-1
    const int nA = BB * K_ACT;
    const bool isB = (g >= nA);
    if (isB) g -= nA;
    const int b = g / K_ACT;
    int t = (isB ? idxB : idxA)[g];
    t = min(max(t, 0), TT - 1);
    const float4* src = (const float4*)(x + (size_t)(b * TT + t) * FF);
    float4* dst = (float4*)((isB ? featB : featA) + (size_t)g * FF);
    for (int i = threadIdx.x; i < FF / 4; i += 256) dst[i] = src[i];
}

// ---------------------------------------------------------------------------
// K4: mean of top-93 of each cas column  -> meansA[b][c]
// ---------------------------------------------------------------------------
__global__ __launch_bounds__(256) void k_colmean(
    const float* __restrict__ cas_ws, float* __restrict__ meansA)
{
    const int b = blockIdx.x / CC;
    const int c = blockIdx.x % CC;
    const int tid = threadIdx.x;

    __shared__ float col[TT];
    __shared__ float pred[256];

    for (int t = tid; t < TT; t += 256) col[t] = cas_ws[(size_t)(b * TT + t) * CC + c];
    __syncthreads();

    float loc = 0.f;
    for (int t = tid; t < TT; t += 256) {
        const float v = col[t];
        int cnt = 0;
        for (int u = 0; u < TT; ++u) {
            const float wv = col[u];
            cnt += (wv > v) || (wv == v && u < t);
        }
        if (cnt < K_ACT) loc += v;
    }
    pred[tid] = loc;
    __syncthreads();
    for (int s = 128; s > 0; s >>= 1) {
        if (tid < s) pred[tid] += pred[tid + s];
        __syncthreads();
    }
    if (tid == 0) meansA[b * CC + c] = pred[0] / (float)K_ACT;
}

// ---------------------------------------------------------------------------
// K5: score_bkg mean over idxB rows + softmaxes for both scores
// ---------------------------------------------------------------------------
__global__ void k_scores(
    const float* __restrict__ cas_ws, const float* __restrict__ meansA,
    const int* __restrict__ idxB, float* __restrict__ score_act,
    float* __restrict__ score_bkg)
{
    const int b = blockIdx.x;
    const int tid = threadIdx.x;
    __shared__ float mB[CC];

    if (tid < CC) {
        float s = 0.f;
        for (int j = 0; j < K_BKG; ++j) {
            int t = idxB[b * K_BKG + j];
            t = min(max(t, 0), TT - 1);
            s += cas_ws[(size_t)(b * TT + t) * CC + tid];
        }
        mB[tid] = s / (float)K_BKG;
    }
    __syncthreads();
    if (tid == 0) {
        float va[CC], vb[CC];
        float ma = -1e30f, sa = 0.f;
        for (int c = 0; c < CC; ++c) { va[c] = meansA[b * CC + c]; ma = fmaxf(ma, va[c]); }
        for (int c = 0; c < CC; ++c) { va[c] = expf(va[c] - ma); sa += va[c]; }
        for (int c = 0; c < CC; ++c) score_act[b * CC + c] = va[c] / sa;
        float mb = -1e30f, sb = 0.f;
        for (int c = 0; c < CC; ++c) { vb[c] = mB[c]; mb = fmaxf(mb, vb[c]); }
        for (int c = 0; c < CC; ++c) { vb[c] = expf(vb[c] - mb); sb += vb[c]; }
        for (int c = 0; c < CC; ++c) score_bkg[b * CC + c] = vb[c] / sb;
    }
}

// ---------------------------------------------------------------------------
// K6: cas_softmax over C per (b,t) row — IN PLACE on the cas logits, which
// live in the cas_softmax output region (saves workspace + one write pass)
// ---------------------------------------------------------------------------
__global__ __launch_bounds__(256) void k_cassm(float* __restrict__ cas)
{
    const int row = blockIdx.x * 256 + threadIdx.x;
    if (row >= NROWS) return;
    float4* p = (float4*)(cas + (size_t)row * CC);
    float v[CC];
#pragma unroll
    for (int i = 0; i < 5; ++i) {
        const float4 q = p[i];
        v[4 * i] = q.x; v[4 * i + 1] = q.y; v[4 * i + 2] = q.z; v[4 * i + 3] = q.w;
    }
    float m = v[0];
#pragma unroll
    for (int c = 1; c < CC; ++c) m = fmaxf(m, v[c]);
    float s = 0.f;
#pragma unroll
    for (int c = 0; c < CC; ++c) { v[c] = expf(v[c] - m); s += v[c]; }
    const float inv = 1.f / s;
#pragma unroll
    for (int i = 0; i < 5; ++i) {
        float4 q;
        q.x = v[4 * i] * inv; q.y = v[4 * i + 1] * inv;
        q.z = v[4 * i + 2] * inv; q.w = v[4 * i + 3] * inv;
        p[i] = q;
    }
}

extern "C" void kernel_launch(void* const* d_in, const int* in_sizes, int n_in,
                              void* d_out, int out_size, void* d_ws, size_t ws_size,
                              hipStream_t stream)
{
    const float* x     = (const float*)d_in[0];
    const float* w     = (const float*)d_in[1];
    const float* mask  = (const float*)d_in[2];
    const float* smask = (const float*)d_in[3];
    float* out = (float*)d_out;

    // workspace (tiny, ~110 KB): fp64 mag^2, index lists, class means
    char* ws = (char*)d_ws;
    double* mag2_ws = (double*)ws;                  // 12000*8 = 96000 B
    int*    idxA    = (int*)(ws + 96000);           // 1488*4
    int*    idxB    = (int*)(ws + 101952);          // 1488*4
    float*  meansA  = (float*)(ws + 107904);        // 320*4

    // output layout (f32 elements), reference return order
    float* score_act = out;                                    // 320
    float* score_bkg = out + 320;                              // 320
    float* featA     = out + 640;                              // 16*93*4096
    float* featB     = featA + (size_t)BB * K_ACT * FF;
    float* features  = featB + (size_t)BB * K_BKG * FF;        // 16*750*4096
    float* cas_buf   = features + (size_t)BB * TT * FF;        // 16*750*20: logits then softmax in place

    k_main<<<NROWS / 4, 256, 0, stream>>>(x, w, mask, features, cas_buf, mag2_ws);
    k_topk<<<dim3(BB, 3), 256, 0, stream>>>(mag2_ws, smask, idxA, idxB);
    k_gather<<<2 * BB * K_ACT, 256, 0, stream>>>(x, idxA, idxB, featA, featB);
    k_colmean<<<BB * CC, 256, 0, stream>>>(cas_buf, meansA);
    k_scores<<<BB, 64, 0, stream>>>(cas_buf, meansA, idxB, score_act, score_bkg);
    k_cassm<<<(NROWS + 255) / 256, 256, 0, stream>>>(cas_buf);
}